// Round 2
// 71.130 us; speedup vs baseline: 1.0089x; 1.0089x over previous
//
#include <hip/hip_runtime.h>

#define BIG 1e9f

typedef float f4 __attribute__((ext_vector_type(4)));

// ---- asm macros -----------------------------------------------------------
// RD2(W): running unclamped LDS byte addr au += 256 (next row); clamp to
//         [row0, row63] with one med3 (sb = base+lane*4, hi = sb+63*256);
//         issue ds_read_b32 for diag k+12.
#define RD2(W) \
    "v_add_u32 %[au], 0x100, %[au]\n\t" \
    "v_med3_i32 %[ad], %[au], %[sb], %[hi]\n\t" \
    "ds_read_b32 " W ", %[ad]\n\t"

// CM2(W,XW,XS): x = wave_shr:1(e). No bound_ctrl => lane 0 dest is PRESERVED,
// and since XW/XS are only ever written by this DPP, lane 0 keeps its initial
// BIG forever (no per-slot re-init needed). Then e = min3(left,up,diag) + w.
#define CM2(W, XW, XS) \
    "v_mov_b32_dpp " XW ", %[e] wave_shr:1 row_mask:0xf bank_mask:0xf\n\t" \
    "v_min3_f32 %[tp], " XW ", %[e], " XS "\n\t" \
    "v_add_f32 %[e], %[tp], " W "\n\t"

// One waitcnt per TWO slots: 12 ds_reads outstanding; lgkmcnt(10) leaves at
// most 10 DS ops in flight. Any consumed w has >=11 newer DS ops (reads from
// the 5.5 pairs since it was issued, plus any interleaved ds_writes), so
// <=10 outstanding guarantees it retired -- the invariant is write-agnostic.
#define PAIR(WiA, WcA, WiB, WcB, XN, XO) \
    "s_waitcnt lgkmcnt(10)\n\t" \
    RD2(WiA) CM2(WcA, XN, XO) \
    RD2(WiB) CM2(WcB, XO, XN)

// One asm statement = 14 DP slots (7 pairs); slot issues the read for diag
// k+12 into w[(s+12)%14] and consumes w[s%14]; x0/x1 alternate per slot.
#define BODY14 \
    asm volatile( \
        PAIR("%[w13]", "%[w1]",  "%[w0]",  "%[w2]",  "%[x0]", "%[x1]") \
        PAIR("%[w1]",  "%[w3]",  "%[w2]",  "%[w4]",  "%[x0]", "%[x1]") \
        PAIR("%[w3]",  "%[w5]",  "%[w4]",  "%[w6]",  "%[x0]", "%[x1]") \
        PAIR("%[w5]",  "%[w7]",  "%[w6]",  "%[w8]",  "%[x0]", "%[x1]") \
        PAIR("%[w7]",  "%[w9]",  "%[w8]",  "%[w10]", "%[x0]", "%[x1]") \
        PAIR("%[w9]",  "%[w11]", "%[w10]", "%[w12]", "%[x0]", "%[x1]") \
        PAIR("%[w11]", "%[w13]", "%[w12]", "%[w0]",  "%[x0]", "%[x1]") \
        : [e]"+v"(e), [x0]"+v"(x0), [x1]"+v"(x1), [tp]"+v"(tp), \
          [au]"+v"(au), [ad]"+v"(ad), \
          [w0]"+v"(w0), [w1]"+v"(w1), [w2]"+v"(w2), [w3]"+v"(w3), \
          [w4]"+v"(w4), [w5]"+v"(w5), [w6]"+v"(w6), [w7]"+v"(w7), \
          [w8]"+v"(w8), [w9]"+v"(w9), [w10]"+v"(w10), [w11]"+v"(w11), \
          [w12]"+v"(w12), [w13]"+v"(w13) \
        : [sb]"v"(sb), [hi]"v"(hi) \
        : "memory")

// One 64-lane wave per sample; lane j owns column j; anti-diagonal sweep with
// potential transform e[v] = d[v] + img[v]/2:
//   e[v] = img[v] + min3(e_left, e_up, e_diag);  out = e_final - img[63][63]/2.
// Staging v2 (reg-staged, T14 split): 16x global_load_dwordx4 -> VGPRs issued
// up-front (compiler emits counted s_waitcnt vmcnt(N)), then ds_write_b128
// group-by-group between DP blocks. Same-wave DS ops execute in order, so a
// write group issued before a BODY precedes that BODY's ds_reads -- replaces
// the previous global_load_lds + explicit vmcnt(9/5/2/0) gating.
__global__ __launch_bounds__(128) void dp_diag_kernel(const float* __restrict__ img,
                                                      float* __restrict__ out, int B) {
    __shared__ __align__(16) float smem[2][4096];   // 16 KB per wave, wave-private
    const int lane = threadIdx.x & 63;
    const int wave = threadIdx.x >> 6;
    const int b = (blockIdx.x << 1) + wave;
    if (b >= B) return;                // uniform per wave; no block barrier used

    float* s = smem[wave];
    const float* g = img + ((size_t)b << 12) + (lane << 2);

    // issue all 16 loads (chunk t = rows 4t..4t+3; lane covers 16 B at lane*4)
    f4 r[16];
    #pragma unroll
    for (int t = 0; t < 16; ++t)
        r[t] = *reinterpret_cast<const f4*>(g + (t << 8));

    // rows 0..31 into LDS (compiler waits vmcnt(8) here, 8 loads still in flight)
    #pragma unroll
    for (int t = 0; t < 8; ++t)
        *reinterpret_cast<f4*>(s + (t << 8) + (lane << 2)) = r[t];

    float e  = (lane == 0) ? 0.5f * r[0].x : BIG;   // diag k=0 state, from reg
    float x0 = BIG, x1 = BIG;   // written ONLY by lane-0-preserving DPP => lane0 stays BIG
    float w0 = 0, w1 = 0, w2 = 0, w3 = 0, w4 = 0, w5 = 0, w6 = 0,
          w7 = 0, w8 = 0, w9 = 0, w10 = 0, w11 = 0, w12 = 0, w13 = 0;
    float tp = 0;
    const int sb = (int)(unsigned)(uintptr_t)s + (lane << 2);  // row-0 byte addr
    const int hi = sb + 16128;                                 // row-63 byte addr
    int au = sb - (lane << 8);   // unclamped addr for diag 0 (pre-increment)
    int ad = 0;

    // prologue: issue ds_reads for diagonals k = 1..12 (rows <= 12) into w1..w12
    asm volatile(
        RD2("%[w1]") RD2("%[w2]") RD2("%[w3]") RD2("%[w4]") RD2("%[w5]") RD2("%[w6]")
        RD2("%[w7]") RD2("%[w8]") RD2("%[w9]") RD2("%[w10]") RD2("%[w11]") RD2("%[w12]")
        "s_nop 2\n\t"
        : [au]"+v"(au), [ad]"+v"(ad),
          [w1]"+v"(w1), [w2]"+v"(w2), [w3]"+v"(w3), [w4]"+v"(w4),
          [w5]"+v"(w5), [w6]"+v"(w6), [w7]"+v"(w7), [w8]"+v"(w8),
          [w9]"+v"(w9), [w10]"+v"(w10), [w11]"+v"(w11), [w12]"+v"(w12)
        : [sb]"v"(sb), [hi]"v"(hi)
        : "memory");

    BODY14;                                               // k = 1..14  (reads rows <= 26)

    #pragma unroll
    for (int t = 8; t < 12; ++t)                          // rows 32..47 (waits vmcnt(4))
        *reinterpret_cast<f4*>(s + (t << 8) + (lane << 2)) = r[t];
    BODY14;                                               // k = 15..28 (reads rows <= 40)

    #pragma unroll
    for (int t = 12; t < 16; ++t)                         // rows 48..63 (waits vmcnt(0))
        *reinterpret_cast<f4*>(s + (t << 8) + (lane << 2)) = r[t];
    BODY14;                                               // k = 29..42 (reads rows <= 54)

    BODY14;                                               // k = 43..56
    #pragma unroll 1
    for (int it = 0; it < 5; ++it)                        // k = 57..126
        BODY14;
    asm volatile("s_waitcnt lgkmcnt(0)\n\t" ::: "memory"); // drain 12 dangling reads

    if (lane == 63) out[b] = e - 0.5f * r[15].w;  // d[63][63] from staged reg
}

extern "C" void kernel_launch(void* const* d_in, const int* in_sizes, int n_in,
                              void* d_out, int out_size, void* d_ws, size_t ws_size,
                              hipStream_t stream) {
    const float* img = (const float*)d_in[0];
    float* out = (float*)d_out;
    const int B = out_size;                  // 2048
    const int threads = 128;                 // 2 waves (samples) per block
    const int grid = (B + 1) / 2;
    dp_diag_kernel<<<grid, threads, 0, stream>>>(img, out, B);
}